// Round 4
// baseline (693.959 us; speedup 1.0000x reference)
//
#include <hip/hip_runtime.h>
#include <hip/hip_bf16.h>
#include <stdint.h>

// Problem: B=8192, E=1024, P=512. x:[8192,2048] f32, w:[1024,512] f32, b:[512] f32.
// out: scalar = mean_i( -S[i,i^4096]/T + log(sum_{j!=i} exp(S[i,j]/T)) ),
// S = zn zn^T (symmetric -> upper triangle of 128x128 blocks), T=0.1.
// gemm2: fp8 e4m3 via mfma_scale_f32_16x16x128_f8f6f4, unit scales (0x7F).
// zn8 = fp8(zn*16); epilogue scale 10/256.
//
// ws layout (bytes):
//   wt  bf16 [512][1024]    @ 0
//   xb  bf16 [16384][1024]  @ 1048576
//   z   f32  [16384][512]   @ 34603008
//   zn8 fp8  [8192][1024]   @ 68157440
//   sumexp f32[8192]        @ 84934656
//   pos    f32[8192]        @ 84967424

typedef __attribute__((ext_vector_type(8))) __bf16 bf16x8;
typedef __attribute__((ext_vector_type(4))) float f32x4;
typedef __attribute__((ext_vector_type(4))) int i32x4;
typedef __attribute__((ext_vector_type(8))) int i32x8;

__device__ __forceinline__ unsigned short f2bf(float f) {
  union { float f; unsigned int u; } v; v.f = f;
  unsigned int u = v.u;
  u += 0x7FFFu + ((u >> 16) & 1u);
  return (unsigned short)(u >> 16);
}

// ---------------- prep: xb = bf16(relu(x)); wt = bf16(w^T); sumexp = 0 -------
__global__ __launch_bounds__(256) void prep_kernel(
    const float* __restrict__ x, const float* __restrict__ w,
    unsigned short* __restrict__ xb, unsigned short* __restrict__ wt,
    float* __restrict__ sumexp) {
  int tid = blockIdx.x * 256 + threadIdx.x;
  float4 v = ((const float4*)x)[tid];
  ushort4 o;
  o.x = f2bf(fmaxf(v.x, 0.f));
  o.y = f2bf(fmaxf(v.y, 0.f));
  o.z = f2bf(fmaxf(v.z, 0.f));
  o.w = f2bf(fmaxf(v.w, 0.f));
  ((ushort4*)xb)[tid] = o;
  if (tid < 512 * 1024) {
    int k = tid & 1023, n = tid >> 10;
    wt[(n << 10) + k] = f2bf(w[k * 512 + n]);
  }
  if (tid < 8192) sumexp[tid] = 0.f;
}

// ---------- bf16 BK=32 staging (round-1 proven) ------------------------------
__device__ __forceinline__ void stage_tile32(const unsigned short* __restrict__ g,
                                             int ldg, unsigned short* s, int tid) {
#pragma unroll
  for (int t = 0; t < 2; ++t) {
    int c = t * 256 + tid;
    int row = ((c >> 6) << 4) | (c & 15);
    int kg = (c >> 4) & 3;
    __builtin_amdgcn_global_load_lds(
        (const __attribute__((address_space(1))) void*)(g + row * ldg + kg * 8),
        (__attribute__((address_space(3))) void*)(s + (c & ~63) * 8),
        16, 0, 0);
  }
}

__device__ __forceinline__ bf16x8 frag_ld(const unsigned short* s, int wq, int t, int L) {
  int c = ((wq + t) << 6) | L;
  return *(const bf16x8*)(s + c * 8);
}

// ---------------- GEMM1: z[16384,512] = xb @ wt^T + b (bf16, BK=32) ---------
__global__ __launch_bounds__(256) void gemm1_kernel(
    const unsigned short* __restrict__ xb, const unsigned short* __restrict__ wt,
    const float* __restrict__ bias, float* __restrict__ z) {
  __shared__ unsigned short As[4096] __attribute__((aligned(16)));
  __shared__ unsigned short Bs[4096] __attribute__((aligned(16)));
  int tid = threadIdx.x, L = tid & 63, w = tid >> 6;
  int wm = w >> 1, wn = w & 1;
  int i0 = blockIdx.x * 128, n0 = blockIdx.y * 128;
  f32x4 acc[4][4];
#pragma unroll
  for (int a = 0; a < 4; ++a)
#pragma unroll
    for (int bq = 0; bq < 4; ++bq) acc[a][bq] = (f32x4)0.f;
  const unsigned short* Ag = xb + i0 * 1024;
  const unsigned short* Bg = wt + n0 * 1024;
  for (int k0 = 0; k0 < 1024; k0 += 32) {
    __syncthreads();
    stage_tile32(Ag + k0, 1024, As, tid);
    stage_tile32(Bg + k0, 1024, Bs, tid);
    __syncthreads();
    bf16x8 af[4], bf[4];
#pragma unroll
    for (int t = 0; t < 4; ++t) af[t] = frag_ld(As, wm * 4, t, L);
#pragma unroll
    for (int t = 0; t < 4; ++t) bf[t] = frag_ld(Bs, wn * 4, t, L);
#pragma unroll
    for (int mt = 0; mt < 4; ++mt)
#pragma unroll
      for (int nt = 0; nt < 4; ++nt)
        acc[mt][nt] = __builtin_amdgcn_mfma_f32_16x16x32_bf16(
            af[mt], bf[nt], acc[mt][nt], 0, 0, 0);
  }
  int rbase = i0 + wm * 64 + ((L >> 4) << 2);
  int cbase = n0 + wn * 64 + (L & 15);
#pragma unroll
  for (int nt = 0; nt < 4; ++nt) {
    int n = cbase + nt * 16;
    float bn = bias[n];
#pragma unroll
    for (int mt = 0; mt < 4; ++mt)
#pragma unroll
      for (int r = 0; r < 4; ++r) {
        int i = rbase + mt * 16 + r;
        z[i * 512 + n] = acc[mt][nt][r] + bn;
      }
  }
}

// -------- normalize: zn8 = fp8_e4m3( 16 * z_row / max(||z_row||,eps) ) -------
__global__ __launch_bounds__(256) void norm_kernel(const float* __restrict__ z,
                                                   unsigned char* __restrict__ zn8) {
  int row = blockIdx.x, t = threadIdx.x;
  float4 v = ((const float4*)z)[row * 256 + t];
  float ss = v.x * v.x + v.y * v.y + v.z * v.z + v.w * v.w;
#pragma unroll
  for (int off = 1; off < 64; off <<= 1) ss += __shfl_xor(ss, off);
  __shared__ float red[4];
  if ((t & 63) == 0) red[t >> 6] = ss;
  __syncthreads();
  float tot = red[0] + red[1] + red[2] + red[3];
  float inv = 16.f / fmaxf(sqrtf(tot), 1e-8f);
  int p = __builtin_amdgcn_cvt_pk_fp8_f32(v.x * inv, v.y * inv, 0, false);
  p = __builtin_amdgcn_cvt_pk_fp8_f32(v.z * inv, v.w * inv, p, true);
  ((int*)zn8)[row * 256 + t] = p;
}

// -------- GEMM2 fp8 symmetric: 16x16x128 MX, 4x4 grid, BK=128 ----------------
// LDS tile (16 KB): byte = g*4096 + h*2048 + row*16 holds source
// [row*1024 + k0 + g*32 + h*16, +16), g = k-group of 32, h = 16B half.
// A-frag lane L: m = L&15, k = (L>>4)*32 + j  (j in [0,32), k-ascending regs).
// C/D 16x16: col = L&15, row = (L>>4)*4 + reg (shape-determined, m121-128).
__global__ __launch_bounds__(256, 3) void gemm2_kernel(
    const unsigned char* __restrict__ zn8,
    float* __restrict__ sumexp, float* __restrict__ pos) {
  __shared__ unsigned char As[16384] __attribute__((aligned(16)));
  __shared__ unsigned char Bs[16384] __attribute__((aligned(16)));
  int rem = blockIdx.x, bi = 0;
  while (rem >= 64 - bi) { rem -= 64 - bi; ++bi; }
  int bj = bi + rem;
  bool diag = (bi == bj);
  int i0 = bi * 128, j0 = bj * 128;

  int tid = threadIdx.x, L = tid & 63, w = tid >> 6;
  int wm = w >> 1, wn = w & 1;
  int srow = tid & 127, sh = tid >> 7;            // staging row / 16B-half

  f32x4 acc[4][4];
#pragma unroll
  for (int a = 0; a < 4; ++a)
#pragma unroll
    for (int bq = 0; bq < 4; ++bq) acc[a][bq] = (f32x4)0.f;

  const unsigned char* Ag = zn8 + i0 * 1024 + srow * 1024 + sh * 16;
  const unsigned char* Bg = zn8 + j0 * 1024 + srow * 1024 + sh * 16;
  const unsigned char* Bsrc = diag ? (const unsigned char*)As : (const unsigned char*)Bs;

  for (int k0 = 0; k0 < 1024; k0 += 128) {
    __syncthreads();
#pragma unroll
    for (int t = 0; t < 4; ++t)
      __builtin_amdgcn_global_load_lds(
          (const __attribute__((address_space(1))) void*)(Ag + k0 + t * 32),
          (__attribute__((address_space(3))) void*)(As + t * 4096 + (tid & ~63) * 16),
          16, 0, 0);
    if (!diag) {
#pragma unroll
      for (int t = 0; t < 4; ++t)
        __builtin_amdgcn_global_load_lds(
            (const __attribute__((address_space(1))) void*)(Bg + k0 + t * 32),
            (__attribute__((address_space(3))) void*)(Bs + t * 4096 + (tid & ~63) * 16),
            16, 0, 0);
    }
    __syncthreads();
    int g4k = (L >> 4) * 4096;                    // k-group panel
    int lrow = (L & 15) * 16;
    i32x8 bfr[4];
#pragma unroll
    for (int nt = 0; nt < 4; ++nt) {
      int off = g4k + (wn * 64 + nt * 16) * 16 + lrow;
      i32x4 lo = *(const i32x4*)(Bsrc + off);
      i32x4 hi = *(const i32x4*)(Bsrc + off + 2048);
      bfr[nt] = (i32x8){lo.x, lo.y, lo.z, lo.w, hi.x, hi.y, hi.z, hi.w};
    }
#pragma unroll
    for (int mt = 0; mt < 4; ++mt) {
      int off = g4k + (wm * 64 + mt * 16) * 16 + lrow;
      i32x4 lo = *(const i32x4*)(As + off);
      i32x4 hi = *(const i32x4*)(As + off + 2048);
      i32x8 afr = (i32x8){lo.x, lo.y, lo.z, lo.w, hi.x, hi.y, hi.z, hi.w};
#pragma unroll
      for (int nt = 0; nt < 4; ++nt)
        acc[mt][nt] = __builtin_amdgcn_mfma_scale_f32_16x16x128_f8f6f4(
            afr, bfr[nt], acc[mt][nt], 0, 0,
            0, 0x7F7F7F7F, 0, 0x7F7F7F7F);
    }
  }

  // epilogue (verified round-2 form): s = acc*10/256; diag mask; pos; exp;
  // row-sums (lane bits 0-3) + col-sums (lane bits 4-5) -> atomics.
  const float SC = 10.0f / 256.0f;
  float rs[4][4];
  float cs[4] = {0.f, 0.f, 0.f, 0.f};
#pragma unroll
  for (int mt = 0; mt < 4; ++mt)
#pragma unroll
    for (int r = 0; r < 4; ++r) rs[mt][r] = 0.f;
  int ib = i0 + wm * 64 + ((L >> 4) << 2);
  int jb = j0 + wn * 64 + (L & 15);
#pragma unroll
  for (int mt = 0; mt < 4; ++mt)
#pragma unroll
    for (int nt = 0; nt < 4; ++nt) {
      int j = jb + nt * 16;
#pragma unroll
      for (int r = 0; r < 4; ++r) {
        int i = ib + mt * 16 + r;
        float s = acc[mt][nt][r] * SC;
        if (j == (i ^ 4096)) { pos[i] = s; pos[j] = s; }
        float e = (i == j) ? 0.f : __expf(s);
        rs[mt][r] += e;
        if (!diag) cs[nt] += e;
      }
    }
#pragma unroll
  for (int mt = 0; mt < 4; ++mt)
#pragma unroll
    for (int r = 0; r < 4; ++r) {
      float v = rs[mt][r];
      v += __shfl_xor(v, 1); v += __shfl_xor(v, 2);
      v += __shfl_xor(v, 4); v += __shfl_xor(v, 8);
      rs[mt][r] = v;
    }
  int sel = L & 15;
  float myv = rs[0][0];
#pragma unroll
  for (int mt = 0; mt < 4; ++mt)
#pragma unroll
    for (int r = 0; r < 4; ++r)
      if (sel == mt * 4 + r) myv = rs[mt][r];
  int rowi = i0 + wm * 64 + (sel >> 2) * 16 + ((L >> 4) << 2) + (sel & 3);
  atomicAdd(&sumexp[rowi], myv);
  if (!diag) {
#pragma unroll
    for (int nt = 0; nt < 4; ++nt) {
      float v = cs[nt];
      v += __shfl_xor(v, 16); v += __shfl_xor(v, 32);
      if ((L >> 4) == 0) atomicAdd(&sumexp[jb + nt * 16], v);
    }
  }
}

// ---------------- finalize: out = mean(log(sumexp) - pos) --------------------
__global__ __launch_bounds__(1024) void finalize_kernel(
    const float* __restrict__ sumexp, const float* __restrict__ pos,
    float* __restrict__ out) {
  int t = threadIdx.x;
  float s = 0.f;
  for (int i = t; i < 8192; i += 1024) s += logf(sumexp[i]) - pos[i];
#pragma unroll
  for (int off = 1; off < 64; off <<= 1) s += __shfl_xor(s, off);
  __shared__ float red[16];
  if ((t & 63) == 0) red[t >> 6] = s;
  __syncthreads();
  if (t == 0) {
    float tot = 0.f;
    for (int k2 = 0; k2 < 16; ++k2) tot += red[k2];
    out[0] = tot * (1.0f / 8192.0f);
  }
}

extern "C" void kernel_launch(void* const* d_in, const int* in_sizes, int n_in,
                              void* d_out, int out_size, void* d_ws, size_t ws_size,
                              hipStream_t stream) {
  const float* x = (const float*)d_in[0];
  const float* w = (const float*)d_in[1];
  const float* b = (const float*)d_in[2];
  float* out = (float*)d_out;
  char* ws = (char*)d_ws;
  unsigned short* wt = (unsigned short*)(ws);
  unsigned short* xb = (unsigned short*)(ws + 1048576);
  float* z           = (float*)(ws + 34603008);
  unsigned char* zn8 = (unsigned char*)(ws + 68157440);
  float* sumexp      = (float*)(ws + 84934656);
  float* pos         = (float*)(ws + 84967424);

  prep_kernel<<<16384, 256, 0, stream>>>(x, w, xb, wt, sumexp);
  gemm1_kernel<<<dim3(128, 4), 256, 0, stream>>>(xb, wt, b, z);
  norm_kernel<<<8192, 256, 0, stream>>>(z, zn8);
  gemm2_kernel<<<2080, 256, 0, stream>>>(zn8, sumexp, pos);
  finalize_kernel<<<1, 1024, 0, stream>>>(sumexp, pos, out);
}

// Round 5
// 255.878 us; speedup vs baseline: 2.7121x; 2.7121x over previous
//
#include <hip/hip_runtime.h>
#include <hip/hip_bf16.h>
#include <stdint.h>

// Problem: B=8192, E=1024, P=512. x:[8192,2048] f32, w:[1024,512] f32, b:[512] f32.
// out: scalar = mean_i( -S[i,i^4096]/T + log(sum_{j!=i} exp(S[i,j]/T)) ),
// S = zn zn^T (symmetric -> upper triangle of 128x128 blocks), T=0.1.
// gemm2: fp8 e4m3 via mfma_scale_f32_16x16x128_f8f6f4, unit scales (0x7F).
// zn8 = fp8(zn*16); epilogue scale 10/256.
//
// ws layout (bytes):
//   wt  bf16 [512][1024]    @ 0
//   xb  bf16 [16384][1024]  @ 1048576
//   z   f32  [16384][512]   @ 34603008
//   zn8 fp8  [8192][1024]   @ 68157440
//   sumexp f32[8192]        @ 84934656
//   pos    f32[8192]        @ 84967424

typedef __attribute__((ext_vector_type(8))) __bf16 bf16x8;
typedef __attribute__((ext_vector_type(4))) float f32x4;
typedef __attribute__((ext_vector_type(4))) int i32x4;
typedef __attribute__((ext_vector_type(8))) int i32x8;

__device__ __forceinline__ unsigned short f2bf(float f) {
  union { float f; unsigned int u; } v; v.f = f;
  unsigned int u = v.u;
  u += 0x7FFFu + ((u >> 16) & 1u);
  return (unsigned short)(u >> 16);
}

// ---------------- prep: xb = bf16(relu(x)); wt = bf16(w^T); sumexp = 0 -------
__global__ __launch_bounds__(256) void prep_kernel(
    const float* __restrict__ x, const float* __restrict__ w,
    unsigned short* __restrict__ xb, unsigned short* __restrict__ wt,
    float* __restrict__ sumexp) {
  int tid = blockIdx.x * 256 + threadIdx.x;
  float4 v = ((const float4*)x)[tid];
  ushort4 o;
  o.x = f2bf(fmaxf(v.x, 0.f));
  o.y = f2bf(fmaxf(v.y, 0.f));
  o.z = f2bf(fmaxf(v.z, 0.f));
  o.w = f2bf(fmaxf(v.w, 0.f));
  ((ushort4*)xb)[tid] = o;
  if (tid < 512 * 1024) {
    int k = tid & 1023, n = tid >> 10;
    wt[(n << 10) + k] = f2bf(w[k * 512 + n]);
  }
  if (tid < 8192) sumexp[tid] = 0.f;
}

// ---------- bf16 BK=32 staging (round-1 proven) ------------------------------
__device__ __forceinline__ void stage_tile32(const unsigned short* __restrict__ g,
                                             int ldg, unsigned short* s, int tid) {
#pragma unroll
  for (int t = 0; t < 2; ++t) {
    int c = t * 256 + tid;
    int row = ((c >> 6) << 4) | (c & 15);
    int kg = (c >> 4) & 3;
    __builtin_amdgcn_global_load_lds(
        (const __attribute__((address_space(1))) void*)(g + row * ldg + kg * 8),
        (__attribute__((address_space(3))) void*)(s + (c & ~63) * 8),
        16, 0, 0);
  }
}

__device__ __forceinline__ bf16x8 frag_ld(const unsigned short* s, int wq, int t, int L) {
  int c = ((wq + t) << 6) | L;
  return *(const bf16x8*)(s + c * 8);
}

// ---------------- GEMM1: z[16384,512] = xb @ wt^T + b (bf16, BK=32) ---------
__global__ __launch_bounds__(256) void gemm1_kernel(
    const unsigned short* __restrict__ xb, const unsigned short* __restrict__ wt,
    const float* __restrict__ bias, float* __restrict__ z) {
  __shared__ unsigned short As[4096] __attribute__((aligned(16)));
  __shared__ unsigned short Bs[4096] __attribute__((aligned(16)));
  int tid = threadIdx.x, L = tid & 63, w = tid >> 6;
  int wm = w >> 1, wn = w & 1;
  int i0 = blockIdx.x * 128, n0 = blockIdx.y * 128;
  f32x4 acc[4][4];
#pragma unroll
  for (int a = 0; a < 4; ++a)
#pragma unroll
    for (int bq = 0; bq < 4; ++bq) acc[a][bq] = (f32x4)0.f;
  const unsigned short* Ag = xb + i0 * 1024;
  const unsigned short* Bg = wt + n0 * 1024;
  for (int k0 = 0; k0 < 1024; k0 += 32) {
    __syncthreads();
    stage_tile32(Ag + k0, 1024, As, tid);
    stage_tile32(Bg + k0, 1024, Bs, tid);
    __syncthreads();
    bf16x8 af[4], bf[4];
#pragma unroll
    for (int t = 0; t < 4; ++t) af[t] = frag_ld(As, wm * 4, t, L);
#pragma unroll
    for (int t = 0; t < 4; ++t) bf[t] = frag_ld(Bs, wn * 4, t, L);
#pragma unroll
    for (int mt = 0; mt < 4; ++mt)
#pragma unroll
      for (int nt = 0; nt < 4; ++nt)
        acc[mt][nt] = __builtin_amdgcn_mfma_f32_16x16x32_bf16(
            af[mt], bf[nt], acc[mt][nt], 0, 0, 0);
  }
  int rbase = i0 + wm * 64 + ((L >> 4) << 2);
  int cbase = n0 + wn * 64 + (L & 15);
#pragma unroll
  for (int nt = 0; nt < 4; ++nt) {
    int n = cbase + nt * 16;
    float bn = bias[n];
#pragma unroll
    for (int mt = 0; mt < 4; ++mt)
#pragma unroll
      for (int r = 0; r < 4; ++r) {
        int i = rbase + mt * 16 + r;
        z[i * 512 + n] = acc[mt][nt][r] + bn;
      }
  }
}

// -------- normalize: zn8 = fp8_e4m3( 16 * z_row / max(||z_row||,eps) ) -------
__global__ __launch_bounds__(256) void norm_kernel(const float* __restrict__ z,
                                                   unsigned char* __restrict__ zn8) {
  int row = blockIdx.x, t = threadIdx.x;
  float4 v = ((const float4*)z)[row * 256 + t];
  float ss = v.x * v.x + v.y * v.y + v.z * v.z + v.w * v.w;
#pragma unroll
  for (int off = 1; off < 64; off <<= 1) ss += __shfl_xor(ss, off);
  __shared__ float red[4];
  if ((t & 63) == 0) red[t >> 6] = ss;
  __syncthreads();
  float tot = red[0] + red[1] + red[2] + red[3];
  float inv = 16.f / fmaxf(sqrtf(tot), 1e-8f);
  int p = __builtin_amdgcn_cvt_pk_fp8_f32(v.x * inv, v.y * inv, 0, false);
  p = __builtin_amdgcn_cvt_pk_fp8_f32(v.z * inv, v.w * inv, p, true);
  ((int*)zn8)[row * 256 + t] = p;
}

// -------- GEMM2 fp8 symmetric: 16x16x128 MX, 4x4 grid, BK=128 ----------------
// LDS tile (16 KB) layout [kg][row][32B]: chunk C = kg*256 + row*2 + h holds
// source bytes row*1024 + k0 + kg*32 + h*16 (+16). Each lane's fragment
// (32 B, k-ascending) is CONTIGUOUS -> 2 adjacent ds_read_b128 per frag.
// A-frag lane L: m = L&15, k = (L>>4)*32 + j.
// C/D 16x16: col = L&15, row = (L>>4)*4 + reg (shape-determined, m121-128).
__global__ __launch_bounds__(256) void gemm2_kernel(
    const unsigned char* __restrict__ zn8,
    float* __restrict__ sumexp, float* __restrict__ pos) {
  __shared__ unsigned char As[16384] __attribute__((aligned(16)));
  __shared__ unsigned char Bs[16384] __attribute__((aligned(16)));
  int rem = blockIdx.x, bi = 0;
  while (rem >= 64 - bi) { rem -= 64 - bi; ++bi; }
  int bj = bi + rem;
  bool diag = (bi == bj);
  int i0 = bi * 128, j0 = bj * 128;

  int tid = threadIdx.x, L = tid & 63, w = tid >> 6;
  int wm = w >> 1, wn = w & 1;
  int srow = (tid & 255) >> 1, sh = tid & 1;      // staging row / 16B-half

  f32x4 acc[4][4];
#pragma unroll
  for (int a = 0; a < 4; ++a)
#pragma unroll
    for (int bq = 0; bq < 4; ++bq) acc[a][bq] = (f32x4)0.f;

  const unsigned char* Ag = zn8 + (i0 + srow) * 1024 + sh * 16;
  const unsigned char* Bg = zn8 + (j0 + srow) * 1024 + sh * 16;
  const unsigned char* Bsrc = diag ? (const unsigned char*)As : (const unsigned char*)Bs;

  for (int k0 = 0; k0 < 1024; k0 += 128) {
    __syncthreads();
#pragma unroll
    for (int t = 0; t < 4; ++t)
      __builtin_amdgcn_global_load_lds(
          (const __attribute__((address_space(1))) void*)(Ag + k0 + t * 32),
          (__attribute__((address_space(3))) void*)(As + t * 4096 + (tid & ~63) * 16),
          16, 0, 0);
    if (!diag) {
#pragma unroll
      for (int t = 0; t < 4; ++t)
        __builtin_amdgcn_global_load_lds(
            (const __attribute__((address_space(1))) void*)(Bg + k0 + t * 32),
            (__attribute__((address_space(3))) void*)(Bs + t * 4096 + (tid & ~63) * 16),
            16, 0, 0);
    }
    __syncthreads();
    int g4k = (L >> 4) * 4096;                    // k-group panel
    i32x8 bfr[4];
#pragma unroll
    for (int nt = 0; nt < 4; ++nt) {
      int off = g4k + (wn * 64 + nt * 16 + (L & 15)) * 32;
      i32x4 lo = *(const i32x4*)(Bsrc + off);
      i32x4 hi = *(const i32x4*)(Bsrc + off + 16);
      bfr[nt] = (i32x8){lo.x, lo.y, lo.z, lo.w, hi.x, hi.y, hi.z, hi.w};
    }
#pragma unroll
    for (int mt = 0; mt < 4; ++mt) {
      int off = g4k + (wm * 64 + mt * 16 + (L & 15)) * 32;
      i32x4 lo = *(const i32x4*)(As + off);
      i32x4 hi = *(const i32x4*)(As + off + 16);
      i32x8 afr = (i32x8){lo.x, lo.y, lo.z, lo.w, hi.x, hi.y, hi.z, hi.w};
#pragma unroll
      for (int nt = 0; nt < 4; ++nt)
        acc[mt][nt] = __builtin_amdgcn_mfma_scale_f32_16x16x128_f8f6f4(
            afr, bfr[nt], acc[mt][nt], 0, 0,
            0, 0x7F7F7F7F, 0, 0x7F7F7F7F);
    }
  }

  // epilogue (verified round-2 form): s = acc*10/256; diag mask; pos; exp;
  // row-sums (lane bits 0-3) + col-sums (lane bits 4-5) -> atomics.
  const float SC = 10.0f / 256.0f;
  float rs[4][4];
  float cs[4] = {0.f, 0.f, 0.f, 0.f};
#pragma unroll
  for (int mt = 0; mt < 4; ++mt)
#pragma unroll
    for (int r = 0; r < 4; ++r) rs[mt][r] = 0.f;
  int ib = i0 + wm * 64 + ((L >> 4) << 2);
  int jb = j0 + wn * 64 + (L & 15);
#pragma unroll
  for (int mt = 0; mt < 4; ++mt)
#pragma unroll
    for (int nt = 0; nt < 4; ++nt) {
      int j = jb + nt * 16;
#pragma unroll
      for (int r = 0; r < 4; ++r) {
        int i = ib + mt * 16 + r;
        float s = acc[mt][nt][r] * SC;
        if (j == (i ^ 4096)) { pos[i] = s; pos[j] = s; }
        float e = (i == j) ? 0.f : __expf(s);
        rs[mt][r] += e;
        if (!diag) cs[nt] += e;
      }
    }
#pragma unroll
  for (int mt = 0; mt < 4; ++mt)
#pragma unroll
    for (int r = 0; r < 4; ++r) {
      float v = rs[mt][r];
      v += __shfl_xor(v, 1); v += __shfl_xor(v, 2);
      v += __shfl_xor(v, 4); v += __shfl_xor(v, 8);
      rs[mt][r] = v;
    }
  int sel = L & 15;
  float myv = rs[0][0];
#pragma unroll
  for (int mt = 0; mt < 4; ++mt)
#pragma unroll
    for (int r = 0; r < 4; ++r)
      if (sel == mt * 4 + r) myv = rs[mt][r];
  int rowi = i0 + wm * 64 + (sel >> 2) * 16 + ((L >> 4) << 2) + (sel & 3);
  atomicAdd(&sumexp[rowi], myv);
  if (!diag) {
#pragma unroll
    for (int nt = 0; nt < 4; ++nt) {
      float v = cs[nt];
      v += __shfl_xor(v, 16); v += __shfl_xor(v, 32);
      if ((L >> 4) == 0) atomicAdd(&sumexp[jb + nt * 16], v);
    }
  }
}

// ---------------- finalize: out = mean(log(sumexp) - pos) --------------------
__global__ __launch_bounds__(1024) void finalize_kernel(
    const float* __restrict__ sumexp, const float* __restrict__ pos,
    float* __restrict__ out) {
  int t = threadIdx.x;
  float s = 0.f;
  for (int i = t; i < 8192; i += 1024) s += logf(sumexp[i]) - pos[i];
#pragma unroll
  for (int off = 1; off < 64; off <<= 1) s += __shfl_xor(s, off);
  __shared__ float red[16];
  if ((t & 63) == 0) red[t >> 6] = s;
  __syncthreads();
  if (t == 0) {
    float tot = 0.f;
    for (int k2 = 0; k2 < 16; ++k2) tot += red[k2];
    out[0] = tot * (1.0f / 8192.0f);
  }
}

extern "C" void kernel_launch(void* const* d_in, const int* in_sizes, int n_in,
                              void* d_out, int out_size, void* d_ws, size_t ws_size,
                              hipStream_t stream) {
  const float* x = (const float*)d_in[0];
  const float* w = (const float*)d_in[1];
  const float* b = (const float*)d_in[2];
  float* out = (float*)d_out;
  char* ws = (char*)d_ws;
  unsigned short* wt = (unsigned short*)(ws);
  unsigned short* xb = (unsigned short*)(ws + 1048576);
  float* z           = (float*)(ws + 34603008);
  unsigned char* zn8 = (unsigned char*)(ws + 68157440);
  float* sumexp      = (float*)(ws + 84934656);
  float* pos         = (float*)(ws + 84967424);

  prep_kernel<<<16384, 256, 0, stream>>>(x, w, xb, wt, sumexp);
  gemm1_kernel<<<dim3(128, 4), 256, 0, stream>>>(xb, wt, b, z);
  norm_kernel<<<8192, 256, 0, stream>>>(z, zn8);
  gemm2_kernel<<<2080, 256, 0, stream>>>(zn8, sumexp, pos);
  finalize_kernel<<<1, 1024, 0, stream>>>(sumexp, pos, out);
}

// Round 6
// 206.728 us; speedup vs baseline: 3.3569x; 1.2378x over previous
//
#include <hip/hip_runtime.h>
#include <hip/hip_bf16.h>
#include <stdint.h>

// Problem: B=8192, E=1024, P=512. x:[8192,2048] f32, w:[1024,512] f32, b:[512] f32.
// out: scalar = mean_i( -S[i,i^4096]/T + log(sum_{j!=i} exp(S[i,j]/T)) ),
// S = zn zn^T (symmetric -> upper triangle of 128x128 blocks), T=0.1.
// gemm2: fp8 e4m3 via mfma_scale_f32_16x16x128_f8f6f4, unit scales (0x7F).
// zn8 = fp8(zn*16); epilogue scale 10/256.
//
// ws layout (bytes):
//   wt  bf16 [512][1024]    @ 0
//   xb  bf16 [16384][1024]  @ 1048576
//   z   f32  [16384][512]   @ 34603008
//   zn8 fp8  [8192][1024]   @ 68157440
//   sumexp f32[8192]        @ 84934656
//   pos    f32[8192]        @ 84967424

typedef __attribute__((ext_vector_type(8))) __bf16 bf16x8;
typedef __attribute__((ext_vector_type(4))) float f32x4;
typedef __attribute__((ext_vector_type(4))) int i32x4;
typedef __attribute__((ext_vector_type(8))) int i32x8;

__device__ __forceinline__ unsigned short f2bf(float f) {
  union { float f; unsigned int u; } v; v.f = f;
  unsigned int u = v.u;
  u += 0x7FFFu + ((u >> 16) & 1u);
  return (unsigned short)(u >> 16);
}

// ---------------- prep: xb = bf16(relu(x)); wt = bf16(w^T); sumexp = 0 -------
__global__ __launch_bounds__(256) void prep_kernel(
    const float* __restrict__ x, const float* __restrict__ w,
    unsigned short* __restrict__ xb, unsigned short* __restrict__ wt,
    float* __restrict__ sumexp) {
  int tid = blockIdx.x * 256 + threadIdx.x;
  float4 v = ((const float4*)x)[tid];
  ushort4 o;
  o.x = f2bf(fmaxf(v.x, 0.f));
  o.y = f2bf(fmaxf(v.y, 0.f));
  o.z = f2bf(fmaxf(v.z, 0.f));
  o.w = f2bf(fmaxf(v.w, 0.f));
  ((ushort4*)xb)[tid] = o;
  if (tid < 512 * 1024) {
    int k = tid & 1023, n = tid >> 10;
    wt[(n << 10) + k] = f2bf(w[k * 512 + n]);
  }
  if (tid < 8192) sumexp[tid] = 0.f;
}

// ---------- bf16 BK=32 staging (round-1 proven) ------------------------------
__device__ __forceinline__ void stage_tile32(const unsigned short* __restrict__ g,
                                             int ldg, unsigned short* s, int tid) {
#pragma unroll
  for (int t = 0; t < 2; ++t) {
    int c = t * 256 + tid;
    int row = ((c >> 6) << 4) | (c & 15);
    int kg = (c >> 4) & 3;
    __builtin_amdgcn_global_load_lds(
        (const __attribute__((address_space(1))) void*)(g + row * ldg + kg * 8),
        (__attribute__((address_space(3))) void*)(s + (c & ~63) * 8),
        16, 0, 0);
  }
}

__device__ __forceinline__ bf16x8 frag_ld(const unsigned short* s, int wq, int t, int L) {
  int c = ((wq + t) << 6) | L;
  return *(const bf16x8*)(s + c * 8);
}

// ---------------- GEMM1: z[16384,512] = xb @ wt^T + b (bf16, BK=32) ---------
__global__ __launch_bounds__(256) void gemm1_kernel(
    const unsigned short* __restrict__ xb, const unsigned short* __restrict__ wt,
    const float* __restrict__ bias, float* __restrict__ z) {
  __shared__ unsigned short As[4096] __attribute__((aligned(16)));
  __shared__ unsigned short Bs[4096] __attribute__((aligned(16)));
  int tid = threadIdx.x, L = tid & 63, w = tid >> 6;
  int wm = w >> 1, wn = w & 1;
  int i0 = blockIdx.x * 128, n0 = blockIdx.y * 128;
  f32x4 acc[4][4];
#pragma unroll
  for (int a = 0; a < 4; ++a)
#pragma unroll
    for (int bq = 0; bq < 4; ++bq) acc[a][bq] = (f32x4)0.f;
  const unsigned short* Ag = xb + i0 * 1024;
  const unsigned short* Bg = wt + n0 * 1024;
  for (int k0 = 0; k0 < 1024; k0 += 32) {
    __syncthreads();
    stage_tile32(Ag + k0, 1024, As, tid);
    stage_tile32(Bg + k0, 1024, Bs, tid);
    __syncthreads();
    bf16x8 af[4], bf[4];
#pragma unroll
    for (int t = 0; t < 4; ++t) af[t] = frag_ld(As, wm * 4, t, L);
#pragma unroll
    for (int t = 0; t < 4; ++t) bf[t] = frag_ld(Bs, wn * 4, t, L);
#pragma unroll
    for (int mt = 0; mt < 4; ++mt)
#pragma unroll
      for (int nt = 0; nt < 4; ++nt)
        acc[mt][nt] = __builtin_amdgcn_mfma_f32_16x16x32_bf16(
            af[mt], bf[nt], acc[mt][nt], 0, 0, 0);
  }
  int rbase = i0 + wm * 64 + ((L >> 4) << 2);
  int cbase = n0 + wn * 64 + (L & 15);
#pragma unroll
  for (int nt = 0; nt < 4; ++nt) {
    int n = cbase + nt * 16;
    float bn = bias[n];
#pragma unroll
    for (int mt = 0; mt < 4; ++mt)
#pragma unroll
      for (int r = 0; r < 4; ++r) {
        int i = rbase + mt * 16 + r;
        z[i * 512 + n] = acc[mt][nt][r] + bn;
      }
  }
}

// -------- normalize: zn8 = fp8_e4m3( 16 * z_row / max(||z_row||,eps) ) -------
__global__ __launch_bounds__(256) void norm_kernel(const float* __restrict__ z,
                                                   unsigned char* __restrict__ zn8) {
  int row = blockIdx.x, t = threadIdx.x;
  float4 v = ((const float4*)z)[row * 256 + t];
  float ss = v.x * v.x + v.y * v.y + v.z * v.z + v.w * v.w;
#pragma unroll
  for (int off = 1; off < 64; off <<= 1) ss += __shfl_xor(ss, off);
  __shared__ float red[4];
  if ((t & 63) == 0) red[t >> 6] = ss;
  __syncthreads();
  float tot = red[0] + red[1] + red[2] + red[3];
  float inv = 16.f / fmaxf(sqrtf(tot), 1e-8f);
  int p = __builtin_amdgcn_cvt_pk_fp8_f32(v.x * inv, v.y * inv, 0, false);
  p = __builtin_amdgcn_cvt_pk_fp8_f32(v.z * inv, v.w * inv, p, true);
  ((int*)zn8)[row * 256 + t] = p;
}

// -------- GEMM2 fp8 symmetric: 16x16x128 MX, 4x4 grid, BK=128 ----------------
// LDS tile (16 KB), 4 panels of 256x16B units. Unit u = row*2 + h stored at
// swizzled position p = u ^ ((u>>3)&7)  -> fragment reads hit all 8 bank-quads
// per 8-lane group (conflict-free). Staging keeps wave-uniform base + lane*16;
// lane-side source permutation lp = L ^ ((L>>3)&7) realizes the swizzle.
// A-frag lane L: m = L&15, k = (L>>4)*32 + j. C/D: col=L&15, row=(L>>4)*4+reg.
__global__ __launch_bounds__(256, 3) void gemm2_kernel(
    const unsigned char* __restrict__ zn8,
    float* __restrict__ sumexp, float* __restrict__ pos) {
  __shared__ unsigned char As[16384] __attribute__((aligned(16)));
  __shared__ unsigned char Bs[16384] __attribute__((aligned(16)));
  int rem = blockIdx.x, bi = 0;
  while (rem >= 64 - bi) { rem -= 64 - bi; ++bi; }
  int bj = bi + rem;
  bool diag = (bi == bj);
  int i0 = bi * 128, j0 = bj * 128;

  int tid = threadIdx.x, L = tid & 63, w = tid >> 6;
  int wm = w >> 1, wn = w & 1;
  int l4 = L & 15;
  int panel = (L >> 4) * 4096;

  // swizzled staging source: position P = w*64 + L  ->  u = w*64 + lp
  int lp = L ^ ((L >> 3) & 7);
  int srow = w * 32 + (lp >> 1), sh = lp & 1;

  f32x4 acc[4][4];
#pragma unroll
  for (int a = 0; a < 4; ++a)
#pragma unroll
    for (int bq = 0; bq < 4; ++bq) acc[a][bq] = (f32x4)0.f;

  const unsigned char* Ag = zn8 + (i0 + srow) * 1024 + sh * 16;
  const unsigned char* Bg = zn8 + (j0 + srow) * 1024 + sh * 16;
  const unsigned char* Bsrc = diag ? (const unsigned char*)As : (const unsigned char*)Bs;

#pragma unroll 1
  for (int k0 = 0; k0 < 1024; k0 += 128) {
    __syncthreads();
#pragma unroll
    for (int t = 0; t < 4; ++t)
      __builtin_amdgcn_global_load_lds(
          (const __attribute__((address_space(1))) void*)(Ag + k0 + t * 32),
          (__attribute__((address_space(3))) void*)(As + t * 4096 + (tid & ~63) * 16),
          16, 0, 0);
    if (!diag) {
#pragma unroll
      for (int t = 0; t < 4; ++t)
        __builtin_amdgcn_global_load_lds(
            (const __attribute__((address_space(1))) void*)(Bg + k0 + t * 32),
            (__attribute__((address_space(3))) void*)(Bs + t * 4096 + (tid & ~63) * 16),
            16, 0, 0);
    }
    __syncthreads();
    // preload A fragments (swizzled positions)
    i32x8 afr[4];
#pragma unroll
    for (int mt = 0; mt < 4; ++mt) {
      int row = wm * 64 + mt * 16 + l4;
      int p0 = (row * 2) ^ ((row >> 2) & 7);
      i32x4 lo = *(const i32x4*)(As + panel + p0 * 16);
      i32x4 hi = *(const i32x4*)(As + panel + (p0 ^ 1) * 16);
      afr[mt] = (i32x8){lo.x, lo.y, lo.z, lo.w, hi.x, hi.y, hi.z, hi.w};
    }
#pragma unroll
    for (int nt = 0; nt < 4; ++nt) {
      int row = wn * 64 + nt * 16 + l4;
      int p0 = (row * 2) ^ ((row >> 2) & 7);
      i32x4 lo = *(const i32x4*)(Bsrc + panel + p0 * 16);
      i32x4 hi = *(const i32x4*)(Bsrc + panel + (p0 ^ 1) * 16);
      i32x8 bfr = (i32x8){lo.x, lo.y, lo.z, lo.w, hi.x, hi.y, hi.z, hi.w};
#pragma unroll
      for (int mt = 0; mt < 4; ++mt)
        acc[mt][nt] = __builtin_amdgcn_mfma_scale_f32_16x16x128_f8f6f4(
            afr[mt], bfr, acc[mt][nt], 0, 0,
            0, 0x7F7F7F7F, 0, 0x7F7F7F7F);
    }
  }

  // epilogue (verified): s = acc*10/256; diag mask; pos; exp;
  // row-sums (lane bits 0-3) + col-sums (lane bits 4-5) -> atomics.
  const float SC = 10.0f / 256.0f;
  float rs[4][4];
  float cs[4] = {0.f, 0.f, 0.f, 0.f};
#pragma unroll
  for (int mt = 0; mt < 4; ++mt)
#pragma unroll
    for (int r = 0; r < 4; ++r) rs[mt][r] = 0.f;
  int ib = i0 + wm * 64 + ((L >> 4) << 2);
  int jb = j0 + wn * 64 + l4;
#pragma unroll
  for (int mt = 0; mt < 4; ++mt)
#pragma unroll
    for (int nt = 0; nt < 4; ++nt) {
      int j = jb + nt * 16;
#pragma unroll
      for (int r = 0; r < 4; ++r) {
        int i = ib + mt * 16 + r;
        float s = acc[mt][nt][r] * SC;
        if (j == (i ^ 4096)) { pos[i] = s; pos[j] = s; }
        float e = (i == j) ? 0.f : __expf(s);
        rs[mt][r] += e;
        if (!diag) cs[nt] += e;
      }
    }
#pragma unroll
  for (int mt = 0; mt < 4; ++mt)
#pragma unroll
    for (int r = 0; r < 4; ++r) {
      float v = rs[mt][r];
      v += __shfl_xor(v, 1); v += __shfl_xor(v, 2);
      v += __shfl_xor(v, 4); v += __shfl_xor(v, 8);
      rs[mt][r] = v;
    }
  int sel = l4;
  float myv = rs[0][0];
#pragma unroll
  for (int mt = 0; mt < 4; ++mt)
#pragma unroll
    for (int r = 0; r < 4; ++r)
      if (sel == mt * 4 + r) myv = rs[mt][r];
  int rowi = i0 + wm * 64 + (sel >> 2) * 16 + ((L >> 4) << 2) + (sel & 3);
  atomicAdd(&sumexp[rowi], myv);
  if (!diag) {
#pragma unroll
    for (int nt = 0; nt < 4; ++nt) {
      float v = cs[nt];
      v += __shfl_xor(v, 16); v += __shfl_xor(v, 32);
      if ((L >> 4) == 0) atomicAdd(&sumexp[jb + nt * 16], v);
    }
  }
}

// ---------------- finalize: out = mean(log(sumexp) - pos) --------------------
__global__ __launch_bounds__(1024) void finalize_kernel(
    const float* __restrict__ sumexp, const float* __restrict__ pos,
    float* __restrict__ out) {
  int t = threadIdx.x;
  float s = 0.f;
  for (int i = t; i < 8192; i += 1024) s += logf(sumexp[i]) - pos[i];
#pragma unroll
  for (int off = 1; off < 64; off <<= 1) s += __shfl_xor(s, off);
  __shared__ float red[16];
  if ((t & 63) == 0) red[t >> 6] = s;
  __syncthreads();
  if (t == 0) {
    float tot = 0.f;
    for (int k2 = 0; k2 < 16; ++k2) tot += red[k2];
    out[0] = tot * (1.0f / 8192.0f);
  }
}

extern "C" void kernel_launch(void* const* d_in, const int* in_sizes, int n_in,
                              void* d_out, int out_size, void* d_ws, size_t ws_size,
                              hipStream_t stream) {
  const float* x = (const float*)d_in[0];
  const float* w = (const float*)d_in[1];
  const float* b = (const float*)d_in[2];
  float* out = (float*)d_out;
  char* ws = (char*)d_ws;
  unsigned short* wt = (unsigned short*)(ws);
  unsigned short* xb = (unsigned short*)(ws + 1048576);
  float* z           = (float*)(ws + 34603008);
  unsigned char* zn8 = (unsigned char*)(ws + 68157440);
  float* sumexp      = (float*)(ws + 84934656);
  float* pos         = (float*)(ws + 84967424);

  prep_kernel<<<16384, 256, 0, stream>>>(x, w, xb, wt, sumexp);
  gemm1_kernel<<<dim3(128, 4), 256, 0, stream>>>(xb, wt, b, z);
  norm_kernel<<<8192, 256, 0, stream>>>(z, zn8);
  gemm2_kernel<<<2080, 256, 0, stream>>>(zn8, sumexp, pos);
  finalize_kernel<<<1, 1024, 0, stream>>>(sumexp, pos, out);
}